// Round 6
// baseline (268.031 us; speedup 1.0000x reference)
//
#include <hip/hip_runtime.h>
#include <stdint.h>

typedef __bf16 bf16_t;
typedef _Float16 f16_t;
typedef bf16_t bf16x8 __attribute__((ext_vector_type(8)));
typedef bf16_t bf16x4 __attribute__((ext_vector_type(4)));
typedef f16_t  f16x8  __attribute__((ext_vector_type(8)));
typedef f16_t  f16x4  __attribute__((ext_vector_type(4)));
typedef float floatx4 __attribute__((ext_vector_type(4)));

static constexpr int NB  = 16;
static constexpr int NC  = 512;
static constexpr int NHW = 1024;
static constexpr int NG  = 32;
static constexpr int CPG = 16;

#define SCALE 0.044194173824159216f  // 512^-0.5
#define LOG2E 1.4426950408889634f

// ---------------- GroupNorm stats ----------------
__global__ __launch_bounds__(256) void gn_stats_k(const float* __restrict__ x,
                                                  float* __restrict__ stats) {
  int bg = blockIdx.x;
  const float* xp = x + (size_t)bg * CPG * NHW;
  float s = 0.f, ss = 0.f;
  for (int i = threadIdx.x * 4; i < CPG * NHW; i += 256 * 4) {
    float4 v = *(const float4*)&xp[i];
    s += v.x + v.y + v.z + v.w;
    ss += v.x * v.x + v.y * v.y + v.z * v.z + v.w * v.w;
  }
#pragma unroll
  for (int off = 1; off < 64; off <<= 1) {
    s  += __shfl_xor(s,  off, 64);
    ss += __shfl_xor(ss, off, 64);
  }
  __shared__ float red[2][4];
  int wv = threadIdx.x >> 6;
  if ((threadIdx.x & 63) == 0) { red[0][wv] = s; red[1][wv] = ss; }
  __syncthreads();
  if (threadIdx.x == 0) {
    float st  = red[0][0] + red[0][1] + red[0][2] + red[0][3];
    float sst = red[1][0] + red[1][1] + red[1][2] + red[1][3];
    float mean = st * (1.f / 16384.f);
    float var  = sst * (1.f / 16384.f) - mean * mean;
    stats[bg * 2]     = mean;
    stats[bg * 2 + 1] = rsqrtf(var + 1e-6f);
  }
}

// ------------- normalize: hnT[b][n][c] AND hnN[b][c][n] (both bf16) -------------
__global__ __launch_bounds__(256) void gn_apply_k(const float* __restrict__ x,
                                                  const float* __restrict__ gamma,
                                                  const float* __restrict__ beta,
                                                  const float* __restrict__ stats,
                                                  bf16_t* __restrict__ hnT,
                                                  bf16_t* __restrict__ hnN) {
  int bi = blockIdx.z;
  int c0 = blockIdx.y * 32;
  int n0 = blockIdx.x * 32;
  __shared__ float tile[32][33];   // [c_local][n_local]
  int tn = threadIdx.x & 31;
  int tr = threadIdx.x >> 5;  // 0..7
  const float* xb = x + (size_t)bi * NC * NHW;
#pragma unroll
  for (int r = 0; r < 4; r++) {
    int c = c0 + tr + r * 8;
    int g = c >> 4;
    float mean = stats[(bi * NG + g) * 2];
    float rstd = stats[(bi * NG + g) * 2 + 1];
    float ga = gamma[c], be = beta[c];
    float v = xb[(size_t)c * NHW + n0 + tn];
    tile[tr + r * 8][tn] = (v - mean) * rstd * ga + be;
  }
  __syncthreads();
  int rl = threadIdx.x >> 3, ch = (threadIdx.x & 7) * 4;
  // hnT[n][c]
  bf16_t* hb = hnT + (size_t)bi * NHW * NC;
  bf16x4 pk;
#pragma unroll
  for (int i = 0; i < 4; i++) pk[i] = (bf16_t)tile[ch + i][rl];
  *(bf16x4*)&hb[(size_t)(n0 + rl) * NC + c0 + ch] = pk;
  // hnN[c][n]
  bf16_t* hc = hnN + (size_t)bi * NC * NHW;
  bf16x4 pk2;
#pragma unroll
  for (int i = 0; i < 4; i++) pk2[i] = (bf16_t)tile[rl][ch + i];
  *(bf16x4*)&hc[(size_t)(c0 + rl) * NHW + n0 + ch] = pk2;
}

// ------------- weight prep: slot0=W0^T, slot1=W1^T, slot2=W2 (cast), slot3=W3^T -------------
__global__ __launch_bounds__(256) void wtrans_k(const float* __restrict__ W0,
                                                const float* __restrict__ W1,
                                                const float* __restrict__ W2,
                                                const float* __restrict__ W3,
                                                bf16_t* __restrict__ Wt) {
  int w = blockIdx.z;
  const float* W = (w == 0) ? W0 : (w == 1) ? W1 : (w == 2) ? W2 : W3;
  bf16_t* o = Wt + (size_t)w * NC * NC;
  int d0 = blockIdx.x * 32, c0 = blockIdx.y * 32;
  if (w == 2) {  // straight cast copy [c][d]
    int cl = threadIdx.x >> 3, dc = (threadIdx.x & 7) * 4;
    float4 v = *(const float4*)&W[(size_t)(c0 + cl) * NC + d0 + dc];
    bf16x4 pk;
    pk[0] = (bf16_t)v.x; pk[1] = (bf16_t)v.y; pk[2] = (bf16_t)v.z; pk[3] = (bf16_t)v.w;
    *(bf16x4*)&o[(size_t)(c0 + cl) * NC + d0 + dc] = pk;
    return;
  }
  __shared__ float tile[32][33];  // [c_local][d_local]
  int tdx = threadIdx.x & 31, tr = threadIdx.x >> 5;
#pragma unroll
  for (int r = 0; r < 4; r++)
    tile[tr + r * 8][tdx] = W[(size_t)(c0 + tr + r * 8) * NC + d0 + tdx];
  __syncthreads();
  int dl = threadIdx.x >> 3, cc = (threadIdx.x & 7) * 4;
  bf16x4 pk;
#pragma unroll
  for (int i = 0; i < 4; i++) pk[i] = (bf16_t)tile[cc + i][dl];
  *(bf16x4*)&o[(size_t)(d0 + dl) * NC + c0 + cc] = pk;
}

// ------------- combined bias: bb[e] = sum_d b2[d]*W3[d][e] + b3[e] (fp32) -------------
__global__ __launch_bounds__(256) void bias_k(const float* __restrict__ b2,
                                              const float* __restrict__ W3,
                                              const float* __restrict__ b3,
                                              float* __restrict__ bb) {
  int e = blockIdx.x * 256 + threadIdx.x;
  float s = b3[e];
  for (int d = 0; d < NC; d++) s += b2[d] * W3[(size_t)d * NC + e];
  bb[e] = s;
}

// ---------------- async global->LDS, 16B per lane ----------------
__device__ __forceinline__ void glds16(const bf16_t* g, bf16_t* lds) {
  __builtin_amdgcn_global_load_lds(
      (const __attribute__((address_space(1))) unsigned int*)g,
      (__attribute__((address_space(3))) unsigned int*)lds, 16, 0, 0);
}

__device__ __forceinline__ floatx4 mfma_bf16(bf16x8 a, bf16x8 b, floatx4 c) {
  return __builtin_amdgcn_mfma_f32_16x16x32_bf16(a, b, c, 0, 0, 0);
}

// ---------------- 128x128xBK=64 MFMA GEMM core, XOR-swizzled LDS ----------------
template<int KDIM, bool SWAP>
__device__ __forceinline__ void gemm_core(const bf16_t* __restrict__ A,
                                          const bf16_t* __restrict__ B,
                                          int m0, int n0,
                                          floatx4 (&acc)[4][4]) {
  __shared__ bf16_t As[128 * 64];
  __shared__ bf16_t Bs[128 * 64];
  const int tid = threadIdx.x, lane = tid & 63, wv = tid >> 6;
  const int l16 = lane & 15, quad = lane >> 4;
  const int wm = wv & 1, wn = wv >> 1;
  const int x7 = l16 & 7;

  const int srow = lane >> 3;               // 0..7
  const int schunk = (lane & 7) ^ srow;     // swizzled global chunk
  const bf16_t* aptr = A + (size_t)(m0 + wv * 32 + srow) * KDIM + schunk * 8;
  const bf16_t* bptr = B + (size_t)(n0 + wv * 32 + srow) * KDIM + schunk * 8;
  bf16_t* as_ = &As[(wv * 32) * 64];
  bf16_t* bs_ = &Bs[(wv * 32) * 64];

  for (int k0 = 0; k0 < KDIM; k0 += 64) {
    __syncthreads();
#pragma unroll
    for (int i = 0; i < 4; i++) {
      glds16(aptr + (size_t)(8 * i) * KDIM, as_ + (8 * i) * 64);
      glds16(bptr + (size_t)(8 * i) * KDIM, bs_ + (8 * i) * 64);
    }
    aptr += 64; bptr += 64;
    __syncthreads();
    bf16x8 af[2][4], bfv[2][4];
#pragma unroll
    for (int h = 0; h < 2; h++)
#pragma unroll
      for (int i = 0; i < 4; i++) {
        int q = h * 4 + quad;
        af[h][i]  = *(const bf16x8*)&As[(wm * 64 + i * 16 + l16) * 64 + ((q ^ x7) * 8)];
        bfv[h][i] = *(const bf16x8*)&Bs[(wn * 64 + i * 16 + l16) * 64 + ((q ^ x7) * 8)];
      }
#pragma unroll
    for (int h = 0; h < 2; h++)
#pragma unroll
      for (int i = 0; i < 4; i++)
#pragma unroll
        for (int j = 0; j < 4; j++)
          acc[i][j] = SWAP ? mfma_bf16(bfv[h][j], af[h][i], acc[i][j])
                           : mfma_bf16(af[h][i], bfv[h][j], acc[i][j]);
  }
}

#define ACC_INIT(acc)                                   \
  floatx4 acc[4][4];                                    \
  _Pragma("unroll") for (int i = 0; i < 4; i++)         \
  _Pragma("unroll") for (int j = 0; j < 4; j++)         \
    acc[i][j] = (floatx4){0.f, 0.f, 0.f, 0.f};

// ------------- W23 = W2·W3 as W23t[e][c] (bf16): A=Wt3[e][d], B=W2b[c][d] -------------
__global__ __launch_bounds__(256) void w23_k(const bf16_t* __restrict__ Wt3,
                                             const bf16_t* __restrict__ W2b,
                                             bf16_t* __restrict__ W23t) {
  int n0 = blockIdx.x * 128, m0 = blockIdx.y * 128;  // m=e, n=c
  ACC_INIT(acc);
  gemm_core<NC, false>(Wt3, W2b, m0, n0, acc);
  const int lane = threadIdx.x & 63, wv = threadIdx.x >> 6;
  const int l16 = lane & 15, quad = lane >> 4, wm = wv & 1, wn = wv >> 1;
#pragma unroll
  for (int i = 0; i < 4; i++)
#pragma unroll
    for (int j = 0; j < 4; j++) {
      int row = m0 + wm * 64 + i * 16 + quad * 4;   // e
      int col = n0 + wn * 64 + j * 16 + l16;        // c
#pragma unroll
      for (int r = 0; r < 4; r++)
        W23t[(size_t)(row + r) * NC + col] = (bf16_t)acc[i][j][r];
    }
}

// ------------- Q/K GEMM (SWAP): Qt gets SCALE folded -------------
__global__ __launch_bounds__(256) void gemm_qk_k(const bf16_t* __restrict__ hnT,
                                                 const bf16_t* __restrict__ Wt,
                                                 const float* __restrict__ b0,
                                                 const float* __restrict__ b1,
                                                 bf16_t* __restrict__ Qt,
                                                 bf16_t* __restrict__ Kt) {
  int bz = blockIdx.z, bi = bz & 15, wsel = bz >> 4;   // 0..31
  int n0 = blockIdx.x * 128, m0 = blockIdx.y * 128;
  const bf16_t* A = hnT + (size_t)bi * NHW * NC;
  const bf16_t* B = Wt + (size_t)wsel * NC * NC;
  ACC_INIT(acc);
  gemm_core<NC, true>(A, B, m0, n0, acc);

  const int lane = threadIdx.x & 63, wv = threadIdx.x >> 6;
  const int l16 = lane & 15, quad = lane >> 4, wm = wv & 1, wn = wv >> 1;
  const float* bias = wsel ? b1 : b0;
  const float sc = wsel ? 1.f : SCALE;
  bf16_t* out = (wsel ? Kt : Qt) + (size_t)bi * NHW * NC;
#pragma unroll
  for (int i = 0; i < 4; i++) {
    int m = m0 + wm * 64 + i * 16 + l16;
#pragma unroll
    for (int j = 0; j < 4; j++) {
      int db = n0 + wn * 64 + j * 16 + quad * 4;
      float4 bv = *(const float4*)&bias[db];
      bf16x4 pk;
      pk[0] = (bf16_t)((acc[i][j][0] + bv.x) * sc);
      pk[1] = (bf16_t)((acc[i][j][1] + bv.y) * sc);
      pk[2] = (bf16_t)((acc[i][j][2] + bv.z) * sc);
      pk[3] = (bf16_t)((acc[i][j][3] + bv.w) * sc);
      *(bf16x4*)&out[(size_t)m * NC + db] = pk;
    }
  }
}

// ------------- S GEMM (SWAP): S[i][j] (fp16) = Qs·K^T -------------
__global__ __launch_bounds__(256) void gemm_s_k(const bf16_t* __restrict__ Qt,
                                                const bf16_t* __restrict__ Kt,
                                                f16_t* __restrict__ S) {
  int bi = blockIdx.z;
  int n0 = blockIdx.x * 128, m0 = blockIdx.y * 128;
  const bf16_t* A = Qt + (size_t)bi * NHW * NC;
  const bf16_t* B = Kt + (size_t)bi * NHW * NC;
  ACC_INIT(acc);
  gemm_core<NC, true>(A, B, m0, n0, acc);

  const int lane = threadIdx.x & 63, wv = threadIdx.x >> 6;
  const int l16 = lane & 15, quad = lane >> 4, wm = wv & 1, wn = wv >> 1;
  f16_t* out = S + (size_t)bi * NHW * NHW;
#pragma unroll
  for (int i = 0; i < 4; i++) {
    int m = m0 + wm * 64 + i * 16 + l16;
#pragma unroll
    for (int j = 0; j < 4; j++) {
      int nb = n0 + wn * 64 + j * 16 + quad * 4;
      f16x4 pk;
#pragma unroll
      for (int r = 0; r < 4; r++) pk[r] = (f16_t)(acc[i][j][r]);
      *(f16x4*)&out[(size_t)m * NHW + nb] = pk;
    }
  }
}

// ------------- softmax: one wave per row; P (bf16) overwrites S (fp16) in place -------------
__global__ __launch_bounds__(256) void softmax_k(const f16_t* __restrict__ S,
                                                 bf16_t* __restrict__ P) {
  int row = blockIdx.x * 4 + (threadIdx.x >> 6);
  int lane = threadIdx.x & 63;
  const f16_t* sp = S + (size_t)row * NHW + lane * 16;
  f16x8 a = *(const f16x8*)sp;
  f16x8 b = *(const f16x8*)(sp + 8);
  float v[16];
#pragma unroll
  for (int k = 0; k < 8; k++) { v[k] = (float)a[k]; v[8 + k] = (float)b[k]; }
  float mx = v[0];
#pragma unroll
  for (int k = 1; k < 16; k++) mx = fmaxf(mx, v[k]);
#pragma unroll
  for (int off = 1; off < 64; off <<= 1) mx = fmaxf(mx, __shfl_xor(mx, off, 64));
  float e[16], s = 0.f;
#pragma unroll
  for (int k = 0; k < 16; k++) { e[k] = exp2f((v[k] - mx) * LOG2E); s += e[k]; }
#pragma unroll
  for (int off = 1; off < 64; off <<= 1) s += __shfl_xor(s, off, 64);
  float inv = 1.f / s;
  bf16x8 o0, o1;
#pragma unroll
  for (int k = 0; k < 8; k++) { o0[k] = (bf16_t)(e[k] * inv); o1[k] = (bf16_t)(e[8 + k] * inv); }
  bf16_t* pp = P + (size_t)row * NHW + lane * 16;
  *(bf16x8*)pp = o0;
  *(bf16x8*)(pp + 8) = o1;
}

// ------------- T GEMM (SWAP): T[n][c] = P[n][:]·hnN[c][:], K=1024 -------------
__global__ __launch_bounds__(256) void gemm_t_k(const bf16_t* __restrict__ P,
                                                const bf16_t* __restrict__ hnN,
                                                bf16_t* __restrict__ T) {
  int bi = blockIdx.z;
  int n0 = blockIdx.x * 128, m0 = blockIdx.y * 128;
  const bf16_t* A = P + (size_t)bi * NHW * NHW;
  const bf16_t* B = hnN + (size_t)bi * NC * NHW;
  ACC_INIT(acc);
  gemm_core<NHW, true>(A, B, m0, n0, acc);

  const int lane = threadIdx.x & 63, wv = threadIdx.x >> 6;
  const int l16 = lane & 15, quad = lane >> 4, wm = wv & 1, wn = wv >> 1;
  bf16_t* out = T + (size_t)bi * NHW * NC;
#pragma unroll
  for (int i = 0; i < 4; i++) {
    int m = m0 + wm * 64 + i * 16 + l16;
#pragma unroll
    for (int j = 0; j < 4; j++) {
      int cb = n0 + wn * 64 + j * 16 + quad * 4;
      bf16x4 pk;
#pragma unroll
      for (int r = 0; r < 4; r++) pk[r] = (bf16_t)(acc[i][j][r]);
      *(bf16x4*)&out[(size_t)m * NC + cb] = pk;
    }
  }
}

// ------------- final GEMM: out[d][n] (fp32) = T·W23t + bb + x -------------
__global__ __launch_bounds__(256) void gemm_out_k(const bf16_t* __restrict__ T,
                                                  const bf16_t* __restrict__ W23t,
                                                  const float* __restrict__ bb,
                                                  const float* __restrict__ x,
                                                  float* __restrict__ outp) {
  int bi = blockIdx.z;
  int n0 = blockIdx.x * 128, m0 = blockIdx.y * 128;
  const bf16_t* A = T + (size_t)bi * NHW * NC;
  ACC_INIT(acc);
  gemm_core<NC, false>(A, W23t, m0, n0, acc);

  const int lane = threadIdx.x & 63, wv = threadIdx.x >> 6;
  const int l16 = lane & 15, quad = lane >> 4, wm = wv & 1, wn = wv >> 1;
  const float* xb = x + (size_t)bi * NC * NHW;
  float* ob = outp + (size_t)bi * NC * NHW;
#pragma unroll
  for (int i = 0; i < 4; i++)
#pragma unroll
    for (int j = 0; j < 4; j++) {
      int row = m0 + wm * 64 + i * 16 + quad * 4;  // spatial n
      int col = n0 + wn * 64 + j * 16 + l16;       // channel d
      float bv = bb[col];
      size_t base = (size_t)col * NHW + row;
      float4 xv = *(const float4*)&xb[base];
      float4 pk;
      pk.x = acc[i][j][0] + bv + xv.x;
      pk.y = acc[i][j][1] + bv + xv.y;
      pk.z = acc[i][j][2] + bv + xv.z;
      pk.w = acc[i][j][3] + bv + xv.w;
      *(float4*)&ob[base] = pk;
    }
}

extern "C" void kernel_launch(void* const* d_in, const int* in_sizes, int n_in,
                              void* d_out, int out_size, void* d_ws, size_t ws_size,
                              hipStream_t stream) {
  (void)in_sizes; (void)n_in; (void)out_size; (void)ws_size;
  const float* x     = (const float*)d_in[0];
  const float* gamma = (const float*)d_in[1];
  const float* beta  = (const float*)d_in[2];
  const float* W0    = (const float*)d_in[3];
  const float* b0    = (const float*)d_in[4];
  const float* W1    = (const float*)d_in[5];
  const float* b1    = (const float*)d_in[6];
  const float* W2    = (const float*)d_in[7];
  const float* b2    = (const float*)d_in[8];
  const float* W3    = (const float*)d_in[9];
  const float* b3    = (const float*)d_in[10];
  float* outp = (float*)d_out;

  char* ws = (char*)d_ws;
  const size_t PLANE = (size_t)NB * NHW * NC * sizeof(bf16_t);  // 16 MB
  float* stats = (float*)ws;
  size_t off = 4096;
  bf16_t* hnT = (bf16_t*)(ws + off); off += PLANE;   // reused as T after softmax
  bf16_t* hnN = (bf16_t*)(ws + off); off += PLANE;
  bf16_t* Qt  = (bf16_t*)(ws + off); off += PLANE;
  bf16_t* Kt  = (bf16_t*)(ws + off); off += PLANE;
  bf16_t* Wt  = (bf16_t*)(ws + off); off += 4 * (size_t)NC * NC * sizeof(bf16_t);
  bf16_t* W23t = (bf16_t*)(ws + off); off += (size_t)NC * NC * sizeof(bf16_t);
  float*  bb  = (float*)(ws + off);  off += 4096;
  f16_t*  S   = (f16_t*)(ws + off);  off += (size_t)NB * NHW * NHW * sizeof(f16_t);  // 32 MB
  bf16_t* P   = (bf16_t*)S;   // softmax writes bf16 in place
  bf16_t* T   = hnT;          // hnT dead after gemm_qk

  gn_stats_k<<<NB * NG, 256, 0, stream>>>(x, stats);
  gn_apply_k<<<dim3(32, 16, NB), 256, 0, stream>>>(x, gamma, beta, stats, hnT, hnN);
  wtrans_k<<<dim3(16, 16, 4), 256, 0, stream>>>(W0, W1, W2, W3, Wt);
  w23_k<<<dim3(4, 4, 1), 256, 0, stream>>>(Wt + 3 * (size_t)NC * NC, Wt + 2 * (size_t)NC * NC, W23t);
  bias_k<<<dim3(2), 256, 0, stream>>>(b2, W3, b3, bb);
  gemm_qk_k<<<dim3(4, 8, 32), 256, 0, stream>>>(hnT, Wt, b0, b1, Qt, Kt);
  gemm_s_k<<<dim3(8, 8, NB), 256, 0, stream>>>(Qt, Kt, S);
  softmax_k<<<dim3(NB * NHW / 4), 256, 0, stream>>>(S, P);
  gemm_t_k<<<dim3(4, 8, NB), 256, 0, stream>>>(P, hnN, T);
  gemm_out_k<<<dim3(4, 8, NB), 256, 0, stream>>>(T, W23t, bb, x, outp);
}

// Round 7
// 245.583 us; speedup vs baseline: 1.0914x; 1.0914x over previous
//
#include <hip/hip_runtime.h>
#include <stdint.h>

typedef __bf16 bf16_t;
typedef _Float16 f16_t;
typedef bf16_t bf16x8 __attribute__((ext_vector_type(8)));
typedef bf16_t bf16x4 __attribute__((ext_vector_type(4)));
typedef f16_t  f16x8  __attribute__((ext_vector_type(8)));
typedef f16_t  f16x4  __attribute__((ext_vector_type(4)));
typedef float floatx4 __attribute__((ext_vector_type(4)));

static constexpr int NB  = 16;
static constexpr int NC  = 512;
static constexpr int NHW = 1024;
static constexpr int NG  = 32;
static constexpr int CPG = 16;

#define SCALE 0.044194173824159216f  // 512^-0.5
#define LOG2E 1.4426950408889634f

// ---------------- GroupNorm stats ----------------
__global__ __launch_bounds__(256) void gn_stats_k(const float* __restrict__ x,
                                                  float* __restrict__ stats) {
  int bg = blockIdx.x;
  const float* xp = x + (size_t)bg * CPG * NHW;
  float s = 0.f, ss = 0.f;
  for (int i = threadIdx.x * 4; i < CPG * NHW; i += 256 * 4) {
    float4 v = *(const float4*)&xp[i];
    s += v.x + v.y + v.z + v.w;
    ss += v.x * v.x + v.y * v.y + v.z * v.z + v.w * v.w;
  }
#pragma unroll
  for (int off = 1; off < 64; off <<= 1) {
    s  += __shfl_xor(s,  off, 64);
    ss += __shfl_xor(ss, off, 64);
  }
  __shared__ float red[2][4];
  int wv = threadIdx.x >> 6;
  if ((threadIdx.x & 63) == 0) { red[0][wv] = s; red[1][wv] = ss; }
  __syncthreads();
  if (threadIdx.x == 0) {
    float st  = red[0][0] + red[0][1] + red[0][2] + red[0][3];
    float sst = red[1][0] + red[1][1] + red[1][2] + red[1][3];
    float mean = st * (1.f / 16384.f);
    float var  = sst * (1.f / 16384.f) - mean * mean;
    stats[bg * 2]     = mean;
    stats[bg * 2 + 1] = rsqrtf(var + 1e-6f);
  }
}

// ------------- normalize: hnT[b][n][c] AND hnN[b][c][n] (both bf16) -------------
__global__ __launch_bounds__(256) void gn_apply_k(const float* __restrict__ x,
                                                  const float* __restrict__ gamma,
                                                  const float* __restrict__ beta,
                                                  const float* __restrict__ stats,
                                                  bf16_t* __restrict__ hnT,
                                                  bf16_t* __restrict__ hnN) {
  int bi = blockIdx.z;
  int c0 = blockIdx.y * 32;
  int n0 = blockIdx.x * 32;
  __shared__ float tile[32][33];   // [c_local][n_local]
  int tn = threadIdx.x & 31;
  int tr = threadIdx.x >> 5;  // 0..7
  const float* xb = x + (size_t)bi * NC * NHW;
#pragma unroll
  for (int r = 0; r < 4; r++) {
    int c = c0 + tr + r * 8;
    int g = c >> 4;
    float mean = stats[(bi * NG + g) * 2];
    float rstd = stats[(bi * NG + g) * 2 + 1];
    float ga = gamma[c], be = beta[c];
    float v = xb[(size_t)c * NHW + n0 + tn];
    tile[tr + r * 8][tn] = (v - mean) * rstd * ga + be;
  }
  __syncthreads();
  int rl = threadIdx.x >> 3, ch = (threadIdx.x & 7) * 4;
  // hnT[n][c]
  bf16_t* hb = hnT + (size_t)bi * NHW * NC;
  bf16x4 pk;
#pragma unroll
  for (int i = 0; i < 4; i++) pk[i] = (bf16_t)tile[ch + i][rl];
  *(bf16x4*)&hb[(size_t)(n0 + rl) * NC + c0 + ch] = pk;
  // hnN[c][n]
  bf16_t* hc = hnN + (size_t)bi * NC * NHW;
  bf16x4 pk2;
#pragma unroll
  for (int i = 0; i < 4; i++) pk2[i] = (bf16_t)tile[rl][ch + i];
  *(bf16x4*)&hc[(size_t)(c0 + rl) * NHW + n0 + ch] = pk2;
}

// ------------- weight prep phase 1 (z=0..3: W casts / W3^T; z=4: u and bias) -------------
// slots: 0=W0 cast [c][d], 1=W1 cast [c][d], 2=W2 cast [c][d], 3=W3^T [e][d]
// u[c]  = SCALE * sum_d W1[c][d]*b0[d]
// bb[e] = sum_d b2[d]*W3[d][e] + b3[e]
__global__ __launch_bounds__(256) void wprep1_k(const float* __restrict__ W0,
                                                const float* __restrict__ W1,
                                                const float* __restrict__ W2,
                                                const float* __restrict__ W3,
                                                const float* __restrict__ b0,
                                                const float* __restrict__ b2,
                                                const float* __restrict__ b3,
                                                bf16_t* __restrict__ Wt,
                                                float* __restrict__ u,
                                                float* __restrict__ bb) {
  int z = blockIdx.z;
  if (z < 3) {  // cast copy
    const float* W = (z == 0) ? W0 : (z == 1) ? W1 : W2;
    bf16_t* o = Wt + (size_t)z * NC * NC;
    int d0 = blockIdx.x * 32, c0 = blockIdx.y * 32;
    int cl = threadIdx.x >> 3, dc = (threadIdx.x & 7) * 4;
    float4 v = *(const float4*)&W[(size_t)(c0 + cl) * NC + d0 + dc];
    bf16x4 pk;
    pk[0] = (bf16_t)v.x; pk[1] = (bf16_t)v.y; pk[2] = (bf16_t)v.z; pk[3] = (bf16_t)v.w;
    *(bf16x4*)&o[(size_t)(c0 + cl) * NC + d0 + dc] = pk;
    return;
  }
  if (z == 3) {  // W3 transpose
    bf16_t* o = Wt + (size_t)3 * NC * NC;
    int d0 = blockIdx.x * 32, c0 = blockIdx.y * 32;
    __shared__ float tile[32][33];  // [d_local(row of W3)][e_local]
    int tdx = threadIdx.x & 31, tr = threadIdx.x >> 5;
#pragma unroll
    for (int r = 0; r < 4; r++)
      tile[tr + r * 8][tdx] = W3[(size_t)(c0 + tr + r * 8) * NC + d0 + tdx];
    __syncthreads();
    int dl = threadIdx.x >> 3, cc = (threadIdx.x & 7) * 4;
    bf16x4 pk;
#pragma unroll
    for (int i = 0; i < 4; i++) pk[i] = (bf16_t)tile[cc + i][dl];
    *(bf16x4*)&o[(size_t)(d0 + dl) * NC + c0 + cc] = pk;
    return;
  }
  // z == 4 : small reductions
  int bx = blockIdx.x, by = blockIdx.y;
  if (by < 8) {  // u: 128 blocks, 4 waves each -> 4 c's per block
    int cblock = by * 16 + bx;            // 0..127
    int wv = threadIdx.x >> 6, lane = threadIdx.x & 63;
    int c = cblock * 4 + wv;
    const float* wr = W1 + (size_t)c * NC + lane * 8;
    float s = 0.f;
#pragma unroll
    for (int k = 0; k < 8; k++) s += wr[k] * b0[lane * 8 + k];
#pragma unroll
    for (int off = 1; off < 64; off <<= 1) s += __shfl_xor(s, off, 64);
    if (lane == 0) u[c] = SCALE * s;
    return;
  }
  if (by == 8 && bx < 8) {  // bias: 8 blocks x 64 e's
    int e0 = bx * 64;
    int el = threadIdx.x & 63, sl = threadIdx.x >> 6;  // 4 slices of 128 d
    float s = 0.f;
    for (int d = sl * 128; d < sl * 128 + 128; d++)
      s += b2[d] * W3[(size_t)d * NC + e0 + el];
    __shared__ float red[4][64];
    red[sl][el] = s;
    __syncthreads();
    if (threadIdx.x < 64)
      bb[e0 + threadIdx.x] = red[0][threadIdx.x] + red[1][threadIdx.x] +
                             red[2][threadIdx.x] + red[3][threadIdx.x] + b3[e0 + threadIdx.x];
  }
}

// ------------- w[b][j] = hnT[b][j][:] · u (SCALE inside u) -------------
__global__ __launch_bounds__(256) void w_k(const bf16_t* __restrict__ hnT,
                                           const float* __restrict__ u,
                                           float* __restrict__ w) {
  int row = blockIdx.x * 4 + (threadIdx.x >> 6);   // 0..16383
  int lane = threadIdx.x & 63;
  bf16x8 h = *(const bf16x8*)&hnT[(size_t)row * NC + lane * 8];
  const float* up = u + lane * 8;
  float s = 0.f;
#pragma unroll
  for (int k = 0; k < 8; k++) s += (float)h[k] * up[k];
#pragma unroll
  for (int off = 1; off < 64; off <<= 1) s += __shfl_xor(s, off, 64);
  if (lane == 0) w[row] = s;
}

// ---------------- async global->LDS, 16B per lane ----------------
__device__ __forceinline__ void glds16(const bf16_t* g, bf16_t* lds) {
  __builtin_amdgcn_global_load_lds(
      (const __attribute__((address_space(1))) unsigned int*)g,
      (__attribute__((address_space(3))) unsigned int*)lds, 16, 0, 0);
}

__device__ __forceinline__ floatx4 mfma_bf16(bf16x8 a, bf16x8 b, floatx4 c) {
  return __builtin_amdgcn_mfma_f32_16x16x32_bf16(a, b, c, 0, 0, 0);
}

// ---------------- 128x128xBK=64 MFMA GEMM core, XOR-swizzled LDS ----------------
template<int KDIM, bool SWAP>
__device__ __forceinline__ void gemm_core(const bf16_t* __restrict__ A,
                                          const bf16_t* __restrict__ B,
                                          int m0, int n0,
                                          floatx4 (&acc)[4][4]) {
  __shared__ bf16_t As[128 * 64];
  __shared__ bf16_t Bs[128 * 64];
  const int tid = threadIdx.x, lane = tid & 63, wv = tid >> 6;
  const int l16 = lane & 15, quad = lane >> 4;
  const int wm = wv & 1, wn = wv >> 1;
  const int x7 = l16 & 7;

  const int srow = lane >> 3;               // 0..7
  const int schunk = (lane & 7) ^ srow;     // swizzled global chunk
  const bf16_t* aptr = A + (size_t)(m0 + wv * 32 + srow) * KDIM + schunk * 8;
  const bf16_t* bptr = B + (size_t)(n0 + wv * 32 + srow) * KDIM + schunk * 8;
  bf16_t* as_ = &As[(wv * 32) * 64];
  bf16_t* bs_ = &Bs[(wv * 32) * 64];

  for (int k0 = 0; k0 < KDIM; k0 += 64) {
    __syncthreads();
#pragma unroll
    for (int i = 0; i < 4; i++) {
      glds16(aptr + (size_t)(8 * i) * KDIM, as_ + (8 * i) * 64);
      glds16(bptr + (size_t)(8 * i) * KDIM, bs_ + (8 * i) * 64);
    }
    aptr += 64; bptr += 64;
    __syncthreads();
    bf16x8 af[2][4], bfv[2][4];
#pragma unroll
    for (int h = 0; h < 2; h++)
#pragma unroll
      for (int i = 0; i < 4; i++) {
        int q = h * 4 + quad;
        af[h][i]  = *(const bf16x8*)&As[(wm * 64 + i * 16 + l16) * 64 + ((q ^ x7) * 8)];
        bfv[h][i] = *(const bf16x8*)&Bs[(wn * 64 + i * 16 + l16) * 64 + ((q ^ x7) * 8)];
      }
#pragma unroll
    for (int h = 0; h < 2; h++)
#pragma unroll
      for (int i = 0; i < 4; i++)
#pragma unroll
        for (int j = 0; j < 4; j++)
          acc[i][j] = SWAP ? mfma_bf16(bfv[h][j], af[h][i], acc[i][j])
                           : mfma_bf16(af[h][i], bfv[h][j], acc[i][j]);
  }
}

#define ACC_INIT(acc)                                   \
  floatx4 acc[4][4];                                    \
  _Pragma("unroll") for (int i = 0; i < 4; i++)         \
  _Pragma("unroll") for (int j = 0; j < 4; j++)         \
    acc[i][j] = (floatx4){0.f, 0.f, 0.f, 0.f};

// ------------- weight prep phase 2 (z=0: Mt = SCALE*W1·W0^T; z=1: W23t = (W2·W3)^T) -------------
__global__ __launch_bounds__(256) void wprep2_k(const bf16_t* __restrict__ Wt,
                                                bf16_t* __restrict__ Mt,
                                                bf16_t* __restrict__ W23t) {
  int z = blockIdx.z;
  const bf16_t* A = (z == 0) ? (Wt + (size_t)1 * NC * NC) : (Wt + (size_t)3 * NC * NC);
  const bf16_t* B = (z == 0) ? (Wt + (size_t)0 * NC * NC) : (Wt + (size_t)2 * NC * NC);
  bf16_t* out = (z == 0) ? Mt : W23t;
  const float sc = (z == 0) ? SCALE : 1.f;
  int n0 = blockIdx.x * 128, m0 = blockIdx.y * 128;
  ACC_INIT(acc);
  gemm_core<NC, false>(A, B, m0, n0, acc);
  const int lane = threadIdx.x & 63, wv = threadIdx.x >> 6;
  const int l16 = lane & 15, quad = lane >> 4, wm = wv & 1, wn = wv >> 1;
#pragma unroll
  for (int i = 0; i < 4; i++)
#pragma unroll
    for (int j = 0; j < 4; j++) {
      int row = m0 + wm * 64 + i * 16 + quad * 4;
      int col = n0 + wn * 64 + j * 16 + l16;
#pragma unroll
      for (int r = 0; r < 4; r++)
        out[(size_t)(row + r) * NC + col] = (bf16_t)(acc[i][j][r] * sc);
    }
}

// ------------- G GEMM (SWAP): G[i][e] = hnT[i][:]·Mt[e][:], M=16384 one launch -------------
__global__ __launch_bounds__(256) void gemm_g_k(const bf16_t* __restrict__ hnT,
                                                const bf16_t* __restrict__ Mt,
                                                bf16_t* __restrict__ G) {
  int n0 = blockIdx.x * 128, m0 = blockIdx.y * 128;
  ACC_INIT(acc);
  gemm_core<NC, true>(hnT, Mt, m0, n0, acc);
  const int lane = threadIdx.x & 63, wv = threadIdx.x >> 6;
  const int l16 = lane & 15, quad = lane >> 4, wm = wv & 1, wn = wv >> 1;
#pragma unroll
  for (int i = 0; i < 4; i++) {
    int m = m0 + wm * 64 + i * 16 + l16;
#pragma unroll
    for (int j = 0; j < 4; j++) {
      int eb = n0 + wn * 64 + j * 16 + quad * 4;
      bf16x4 pk;
#pragma unroll
      for (int r = 0; r < 4; r++) pk[r] = (bf16_t)(acc[i][j][r]);
      *(bf16x4*)&G[(size_t)m * NC + eb] = pk;
    }
  }
}

// ------------- S GEMM (SWAP): S[i][j] (fp16) = G[i][:]·hnT[j][:] -------------
__global__ __launch_bounds__(256) void gemm_s_k(const bf16_t* __restrict__ G,
                                                const bf16_t* __restrict__ hnT,
                                                f16_t* __restrict__ S) {
  int bi = blockIdx.z;
  int n0 = blockIdx.x * 128, m0 = blockIdx.y * 128;
  const bf16_t* A = G + (size_t)bi * NHW * NC;
  const bf16_t* B = hnT + (size_t)bi * NHW * NC;
  ACC_INIT(acc);
  gemm_core<NC, true>(A, B, m0, n0, acc);

  const int lane = threadIdx.x & 63, wv = threadIdx.x >> 6;
  const int l16 = lane & 15, quad = lane >> 4, wm = wv & 1, wn = wv >> 1;
  f16_t* out = S + (size_t)bi * NHW * NHW;
#pragma unroll
  for (int i = 0; i < 4; i++) {
    int m = m0 + wm * 64 + i * 16 + l16;
#pragma unroll
    for (int j = 0; j < 4; j++) {
      int nb = n0 + wn * 64 + j * 16 + quad * 4;
      f16x4 pk;
#pragma unroll
      for (int r = 0; r < 4; r++) pk[r] = (f16_t)(acc[i][j][r]);
      *(f16x4*)&out[(size_t)m * NHW + nb] = pk;
    }
  }
}

// ------------- softmax with w[j] column bias: P (bf16) overwrites S (fp16) -------------
__global__ __launch_bounds__(256) void softmax_k(const f16_t* __restrict__ S,
                                                 const float* __restrict__ w,
                                                 bf16_t* __restrict__ P) {
  int row = blockIdx.x * 4 + (threadIdx.x >> 6);   // 0..16383
  int lane = threadIdx.x & 63;
  int b = row >> 10;
  const f16_t* sp = S + (size_t)row * NHW + lane * 16;
  const float* wp = w + b * NHW + lane * 16;
  f16x8 a = *(const f16x8*)sp;
  f16x8 bq = *(const f16x8*)(sp + 8);
  float v[16];
#pragma unroll
  for (int k = 0; k < 8; k++) { v[k] = (float)a[k] + wp[k]; v[8 + k] = (float)bq[k] + wp[8 + k]; }
  float mx = v[0];
#pragma unroll
  for (int k = 1; k < 16; k++) mx = fmaxf(mx, v[k]);
#pragma unroll
  for (int off = 1; off < 64; off <<= 1) mx = fmaxf(mx, __shfl_xor(mx, off, 64));
  float e[16], s = 0.f;
#pragma unroll
  for (int k = 0; k < 16; k++) { e[k] = exp2f((v[k] - mx) * LOG2E); s += e[k]; }
#pragma unroll
  for (int off = 1; off < 64; off <<= 1) s += __shfl_xor(s, off, 64);
  float inv = 1.f / s;
  bf16x8 o0, o1;
#pragma unroll
  for (int k = 0; k < 8; k++) { o0[k] = (bf16_t)(e[k] * inv); o1[k] = (bf16_t)(e[8 + k] * inv); }
  bf16_t* pp = P + (size_t)row * NHW + lane * 16;
  *(bf16x8*)pp = o0;
  *(bf16x8*)(pp + 8) = o1;
}

// ------------- T GEMM (SWAP): T[n][c] = P[n][:]·hnN[c][:], K=1024 -------------
__global__ __launch_bounds__(256) void gemm_t_k(const bf16_t* __restrict__ P,
                                                const bf16_t* __restrict__ hnN,
                                                bf16_t* __restrict__ T) {
  int bi = blockIdx.z;
  int n0 = blockIdx.x * 128, m0 = blockIdx.y * 128;
  const bf16_t* A = P + (size_t)bi * NHW * NHW;
  const bf16_t* B = hnN + (size_t)bi * NC * NHW;
  ACC_INIT(acc);
  gemm_core<NHW, true>(A, B, m0, n0, acc);

  const int lane = threadIdx.x & 63, wv = threadIdx.x >> 6;
  const int l16 = lane & 15, quad = lane >> 4, wm = wv & 1, wn = wv >> 1;
  bf16_t* out = T + (size_t)bi * NHW * NC;
#pragma unroll
  for (int i = 0; i < 4; i++) {
    int m = m0 + wm * 64 + i * 16 + l16;
#pragma unroll
    for (int j = 0; j < 4; j++) {
      int cb = n0 + wn * 64 + j * 16 + quad * 4;
      bf16x4 pk;
#pragma unroll
      for (int r = 0; r < 4; r++) pk[r] = (bf16_t)(acc[i][j][r]);
      *(bf16x4*)&out[(size_t)m * NC + cb] = pk;
    }
  }
}

// ------------- final GEMM: out[d][n] (fp32) = T·W23t + bb + x -------------
__global__ __launch_bounds__(256) void gemm_out_k(const bf16_t* __restrict__ T,
                                                  const bf16_t* __restrict__ W23t,
                                                  const float* __restrict__ bb,
                                                  const float* __restrict__ x,
                                                  float* __restrict__ outp) {
  int bi = blockIdx.z;
  int n0 = blockIdx.x * 128, m0 = blockIdx.y * 128;
  const bf16_t* A = T + (size_t)bi * NHW * NC;
  ACC_INIT(acc);
  gemm_core<NC, false>(A, W23t, m0, n0, acc);

  const int lane = threadIdx.x & 63, wv = threadIdx.x >> 6;
  const int l16 = lane & 15, quad = lane >> 4, wm = wv & 1, wn = wv >> 1;
  const float* xb = x + (size_t)bi * NC * NHW;
  float* ob = outp + (size_t)bi * NC * NHW;
#pragma unroll
  for (int i = 0; i < 4; i++)
#pragma unroll
    for (int j = 0; j < 4; j++) {
      int row = m0 + wm * 64 + i * 16 + quad * 4;  // spatial n
      int col = n0 + wn * 64 + j * 16 + l16;       // channel d
      float bv = bb[col];
      size_t base = (size_t)col * NHW + row;
      float4 xv = *(const float4*)&xb[base];
      float4 pk;
      pk.x = acc[i][j][0] + bv + xv.x;
      pk.y = acc[i][j][1] + bv + xv.y;
      pk.z = acc[i][j][2] + bv + xv.z;
      pk.w = acc[i][j][3] + bv + xv.w;
      *(float4*)&ob[base] = pk;
    }
}

extern "C" void kernel_launch(void* const* d_in, const int* in_sizes, int n_in,
                              void* d_out, int out_size, void* d_ws, size_t ws_size,
                              hipStream_t stream) {
  (void)in_sizes; (void)n_in; (void)out_size; (void)ws_size;
  const float* x     = (const float*)d_in[0];
  const float* gamma = (const float*)d_in[1];
  const float* beta  = (const float*)d_in[2];
  const float* W0    = (const float*)d_in[3];
  const float* b0    = (const float*)d_in[4];
  const float* W1    = (const float*)d_in[5];
  const float* b1    = (const float*)d_in[6];  (void)b1;  // cancels in softmax
  const float* W2    = (const float*)d_in[7];
  const float* b2    = (const float*)d_in[8];
  const float* W3    = (const float*)d_in[9];
  const float* b3    = (const float*)d_in[10];
  float* outp = (float*)d_out;

  char* ws = (char*)d_ws;
  const size_t PLANE = (size_t)NB * NHW * NC * sizeof(bf16_t);  // 16 MB
  float* stats = (float*)ws;
  size_t off = 4096;
  bf16_t* hnT = (bf16_t*)(ws + off); off += PLANE;   // reused as T after softmax? no: hnT needed by w_k & S; T uses G slot
  bf16_t* hnN = (bf16_t*)(ws + off); off += PLANE;
  bf16_t* G   = (bf16_t*)(ws + off); off += PLANE;   // reused as T after gemm_s
  bf16_t* Wt  = (bf16_t*)(ws + off); off += 4 * (size_t)NC * NC * sizeof(bf16_t);
  bf16_t* Mt   = (bf16_t*)(ws + off); off += (size_t)NC * NC * sizeof(bf16_t);
  bf16_t* W23t = (bf16_t*)(ws + off); off += (size_t)NC * NC * sizeof(bf16_t);
  float*  u   = (float*)(ws + off);  off += 2048;
  float*  bb  = (float*)(ws + off);  off += 2048;
  float*  w   = (float*)(ws + off);  off += (size_t)NB * NHW * sizeof(float);
  f16_t*  S   = (f16_t*)(ws + off);  off += (size_t)NB * NHW * NHW * sizeof(f16_t);  // 32 MB
  bf16_t* P   = (bf16_t*)S;   // softmax writes bf16 in place
  bf16_t* T   = G;            // G dead after gemm_s

  gn_stats_k<<<NB * NG, 256, 0, stream>>>(x, stats);
  gn_apply_k<<<dim3(32, 16, NB), 256, 0, stream>>>(x, gamma, beta, stats, hnT, hnN);
  wprep1_k<<<dim3(16, 16, 5), 256, 0, stream>>>(W0, W1, W2, W3, b0, b2, b3, Wt, u, bb);
  wprep2_k<<<dim3(4, 4, 2), 256, 0, stream>>>(Wt, Mt, W23t);
  w_k<<<dim3(NB * NHW / 4), 256, 0, stream>>>(hnT, u, w);
  gemm_g_k<<<dim3(4, 128), 256, 0, stream>>>(hnT, Mt, G);
  gemm_s_k<<<dim3(8, 8, NB), 256, 0, stream>>>(G, hnT, S);
  softmax_k<<<dim3(NB * NHW / 4), 256, 0, stream>>>(S, w, P);
  gemm_t_k<<<dim3(4, 8, NB), 256, 0, stream>>>(P, hnN, T);
  gemm_out_k<<<dim3(4, 8, NB), 256, 0, stream>>>(T, W23t, bb, x, outp);
}

// Round 8
// 242.564 us; speedup vs baseline: 1.1050x; 1.0124x over previous
//
#include <hip/hip_runtime.h>
#include <stdint.h>

typedef __bf16 bf16_t;
typedef _Float16 f16_t;
typedef bf16_t bf16x8 __attribute__((ext_vector_type(8)));
typedef bf16_t bf16x4 __attribute__((ext_vector_type(4)));
typedef f16_t  f16x8  __attribute__((ext_vector_type(8)));
typedef f16_t  f16x4  __attribute__((ext_vector_type(4)));
typedef float floatx4 __attribute__((ext_vector_type(4)));

static constexpr int NB  = 16;
static constexpr int NC  = 512;
static constexpr int NHW = 1024;
static constexpr int NG  = 32;
static constexpr int CPG = 16;

#define SCALE 0.044194173824159216f  // 512^-0.5
#define LOG2E 1.4426950408889634f

// ---------------- async global->LDS, 16B per lane ----------------
__device__ __forceinline__ void glds16(const bf16_t* g, bf16_t* lds) {
  __builtin_amdgcn_global_load_lds(
      (const __attribute__((address_space(1))) unsigned int*)g,
      (__attribute__((address_space(3))) unsigned int*)lds, 16, 0, 0);
}

__device__ __forceinline__ floatx4 mfma_bf16(bf16x8 a, bf16x8 b, floatx4 c) {
  return __builtin_amdgcn_mfma_f32_16x16x32_bf16(a, b, c, 0, 0, 0);
}

// ---------------- 128x128xBK=64 MFMA GEMM core, XOR-swizzled LDS ----------------
template<int KDIM, bool SWAP>
__device__ __forceinline__ void gemm_core(const bf16_t* __restrict__ A,
                                          const bf16_t* __restrict__ B,
                                          int m0, int n0,
                                          floatx4 (&acc)[4][4],
                                          bf16_t* As, bf16_t* Bs) {
  const int tid = threadIdx.x, lane = tid & 63, wv = tid >> 6;
  const int l16 = lane & 15, quad = lane >> 4;
  const int wm = wv & 1, wn = wv >> 1;
  const int x7 = l16 & 7;

  const int srow = lane >> 3;               // 0..7
  const int schunk = (lane & 7) ^ srow;     // swizzled global chunk
  const bf16_t* aptr = A + (size_t)(m0 + wv * 32 + srow) * KDIM + schunk * 8;
  const bf16_t* bptr = B + (size_t)(n0 + wv * 32 + srow) * KDIM + schunk * 8;
  bf16_t* as_ = &As[(wv * 32) * 64];
  bf16_t* bs_ = &Bs[(wv * 32) * 64];

  for (int k0 = 0; k0 < KDIM; k0 += 64) {
    __syncthreads();
#pragma unroll
    for (int i = 0; i < 4; i++) {
      glds16(aptr + (size_t)(8 * i) * KDIM, as_ + (8 * i) * 64);
      glds16(bptr + (size_t)(8 * i) * KDIM, bs_ + (8 * i) * 64);
    }
    aptr += 64; bptr += 64;
    __syncthreads();
    bf16x8 af[2][4], bfv[2][4];
#pragma unroll
    for (int h = 0; h < 2; h++)
#pragma unroll
      for (int i = 0; i < 4; i++) {
        int q = h * 4 + quad;
        af[h][i]  = *(const bf16x8*)&As[(wm * 64 + i * 16 + l16) * 64 + ((q ^ x7) * 8)];
        bfv[h][i] = *(const bf16x8*)&Bs[(wn * 64 + i * 16 + l16) * 64 + ((q ^ x7) * 8)];
      }
#pragma unroll
    for (int h = 0; h < 2; h++)
#pragma unroll
      for (int i = 0; i < 4; i++)
#pragma unroll
        for (int j = 0; j < 4; j++)
          acc[i][j] = SWAP ? mfma_bf16(bfv[h][j], af[h][i], acc[i][j])
                           : mfma_bf16(af[h][i], bfv[h][j], acc[i][j]);
  }
}

#define ACC_INIT(acc)                                   \
  floatx4 acc[4][4];                                    \
  _Pragma("unroll") for (int i = 0; i < 4; i++)         \
  _Pragma("unroll") for (int j = 0; j < 4; j++)         \
    acc[i][j] = (floatx4){0.f, 0.f, 0.f, 0.f};

// ------------- prep1: z<3 W casts; z=3 W3^T; z=4 u & bb; z=5,6 GN stats -------------
// slots: 0=W0 [c][d], 1=W1 [c][d], 2=W2 [c][d], 3=W3^T [e][d]
// u[c]  = SCALE * sum_d W1[c][d]*b0[d] ;  bb[e] = sum_d b2[d]*W3[d][e] + b3[e]
__global__ __launch_bounds__(256) void prep1_k(const float* __restrict__ x,
                                               const float* __restrict__ W0,
                                               const float* __restrict__ W1,
                                               const float* __restrict__ W2,
                                               const float* __restrict__ W3,
                                               const float* __restrict__ b0,
                                               const float* __restrict__ b2,
                                               const float* __restrict__ b3,
                                               bf16_t* __restrict__ Wt,
                                               float* __restrict__ u,
                                               float* __restrict__ bb,
                                               float* __restrict__ stats) {
  int z = blockIdx.z;
  if (z >= 5) {  // GroupNorm stats: bg = (z-5)*256 + y*16 + x
    int bg = (z - 5) * 256 + blockIdx.y * 16 + blockIdx.x;
    const float* xp = x + (size_t)bg * CPG * NHW;
    float s = 0.f, ss = 0.f;
    for (int i = threadIdx.x * 4; i < CPG * NHW; i += 256 * 4) {
      float4 v = *(const float4*)&xp[i];
      s += v.x + v.y + v.z + v.w;
      ss += v.x * v.x + v.y * v.y + v.z * v.z + v.w * v.w;
    }
#pragma unroll
    for (int off = 1; off < 64; off <<= 1) {
      s  += __shfl_xor(s,  off, 64);
      ss += __shfl_xor(ss, off, 64);
    }
    __shared__ float red2[2][4];
    int wv = threadIdx.x >> 6;
    if ((threadIdx.x & 63) == 0) { red2[0][wv] = s; red2[1][wv] = ss; }
    __syncthreads();
    if (threadIdx.x == 0) {
      float st  = red2[0][0] + red2[0][1] + red2[0][2] + red2[0][3];
      float sst = red2[1][0] + red2[1][1] + red2[1][2] + red2[1][3];
      float mean = st * (1.f / 16384.f);
      float var  = sst * (1.f / 16384.f) - mean * mean;
      stats[bg * 2]     = mean;
      stats[bg * 2 + 1] = rsqrtf(var + 1e-6f);
    }
    return;
  }
  if (z < 3) {  // cast copy
    const float* W = (z == 0) ? W0 : (z == 1) ? W1 : W2;
    bf16_t* o = Wt + (size_t)z * NC * NC;
    int d0 = blockIdx.x * 32, c0 = blockIdx.y * 32;
    int cl = threadIdx.x >> 3, dc = (threadIdx.x & 7) * 4;
    float4 v = *(const float4*)&W[(size_t)(c0 + cl) * NC + d0 + dc];
    bf16x4 pk;
    pk[0] = (bf16_t)v.x; pk[1] = (bf16_t)v.y; pk[2] = (bf16_t)v.z; pk[3] = (bf16_t)v.w;
    *(bf16x4*)&o[(size_t)(c0 + cl) * NC + d0 + dc] = pk;
    return;
  }
  if (z == 3) {  // W3 transpose
    bf16_t* o = Wt + (size_t)3 * NC * NC;
    int d0 = blockIdx.x * 32, c0 = blockIdx.y * 32;
    __shared__ float tile[32][33];
    int tdx = threadIdx.x & 31, tr = threadIdx.x >> 5;
#pragma unroll
    for (int r = 0; r < 4; r++)
      tile[tr + r * 8][tdx] = W3[(size_t)(c0 + tr + r * 8) * NC + d0 + tdx];
    __syncthreads();
    int dl = threadIdx.x >> 3, cc = (threadIdx.x & 7) * 4;
    bf16x4 pk;
#pragma unroll
    for (int i = 0; i < 4; i++) pk[i] = (bf16_t)tile[cc + i][dl];
    *(bf16x4*)&o[(size_t)(d0 + dl) * NC + c0 + cc] = pk;
    return;
  }
  // z == 4 : small reductions
  int bx = blockIdx.x, by = blockIdx.y;
  if (by < 8) {  // u
    int cblock = by * 16 + bx;            // 0..127
    int wv = threadIdx.x >> 6, lane = threadIdx.x & 63;
    int c = cblock * 4 + wv;
    const float* wr = W1 + (size_t)c * NC + lane * 8;
    float s = 0.f;
#pragma unroll
    for (int k = 0; k < 8; k++) s += wr[k] * b0[lane * 8 + k];
#pragma unroll
    for (int off = 1; off < 64; off <<= 1) s += __shfl_xor(s, off, 64);
    if (lane == 0) u[c] = SCALE * s;
    return;
  }
  if (by == 8 && bx < 8) {  // bb
    int e0 = bx * 64;
    int el = threadIdx.x & 63, sl = threadIdx.x >> 6;
    float s = 0.f;
    for (int d = sl * 128; d < sl * 128 + 128; d++)
      s += b2[d] * W3[(size_t)d * NC + e0 + el];
    __shared__ float red[4][64];
    red[sl][el] = s;
    __syncthreads();
    if (threadIdx.x < 64)
      bb[e0 + threadIdx.x] = red[0][threadIdx.x] + red[1][threadIdx.x] +
                             red[2][threadIdx.x] + red[3][threadIdx.x] + b3[e0 + threadIdx.x];
  }
}

// ------------- prep2: z<NB gn_apply (hnT + hnN); z==NB: Mt / W23t GEMMs -------------
__global__ __launch_bounds__(256) void prep2_k(const float* __restrict__ x,
                                               const float* __restrict__ gamma,
                                               const float* __restrict__ beta,
                                               const float* __restrict__ stats,
                                               const bf16_t* __restrict__ Wt,
                                               bf16_t* __restrict__ hnT,
                                               bf16_t* __restrict__ hnN,
                                               bf16_t* __restrict__ Mt,
                                               bf16_t* __restrict__ W23t) {
  __shared__ bf16_t As[128 * 64];       // gemm path (32 KB)
  __shared__ float tile[32][33];        // gn path (4.2 KB)
  int z = blockIdx.z;
  if (z < NB) {
    int bi = z;
    int c0 = blockIdx.y * 32;
    int n0 = blockIdx.x * 32;
    int tn = threadIdx.x & 31;
    int tr = threadIdx.x >> 5;
    const float* xb = x + (size_t)bi * NC * NHW;
#pragma unroll
    for (int r = 0; r < 4; r++) {
      int c = c0 + tr + r * 8;
      int g = c >> 4;
      float mean = stats[(bi * NG + g) * 2];
      float rstd = stats[(bi * NG + g) * 2 + 1];
      float ga = gamma[c], be = beta[c];
      float v = xb[(size_t)c * NHW + n0 + tn];
      tile[tr + r * 8][tn] = (v - mean) * rstd * ga + be;
    }
    __syncthreads();
    int rl = threadIdx.x >> 3, ch = (threadIdx.x & 7) * 4;
    bf16_t* hb = hnT + (size_t)bi * NHW * NC;
    bf16x4 pk;
#pragma unroll
    for (int i = 0; i < 4; i++) pk[i] = (bf16_t)tile[ch + i][rl];
    *(bf16x4*)&hb[(size_t)(n0 + rl) * NC + c0 + ch] = pk;
    bf16_t* hc = hnN + (size_t)bi * NC * NHW;
    bf16x4 pk2;
#pragma unroll
    for (int i = 0; i < 4; i++) pk2[i] = (bf16_t)tile[rl][ch + i];
    *(bf16x4*)&hc[(size_t)(c0 + rl) * NHW + n0 + ch] = pk2;
    return;
  }
  // z == NB: weight GEMMs; use x<8, y<4
  if (blockIdx.y >= 4 || blockIdx.x >= 8) return;
  __shared__ bf16_t Bs[128 * 64];
  int zz = blockIdx.x >> 2;             // 0: Mt, 1: W23t
  int n0 = (blockIdx.x & 3) * 128, m0 = blockIdx.y * 128;
  const bf16_t* A = (zz == 0) ? (Wt + (size_t)1 * NC * NC) : (Wt + (size_t)3 * NC * NC);
  const bf16_t* B = (zz == 0) ? (Wt + (size_t)0 * NC * NC) : (Wt + (size_t)2 * NC * NC);
  bf16_t* out = (zz == 0) ? Mt : W23t;
  const float sc = (zz == 0) ? SCALE : 1.f;
  ACC_INIT(acc);
  gemm_core<NC, false>(A, B, m0, n0, acc, As, Bs);
  const int lane = threadIdx.x & 63, wv = threadIdx.x >> 6;
  const int l16 = lane & 15, quad = lane >> 4, wm = wv & 1, wn = wv >> 1;
#pragma unroll
  for (int i = 0; i < 4; i++)
#pragma unroll
    for (int j = 0; j < 4; j++) {
      int row = m0 + wm * 64 + i * 16 + quad * 4;
      int col = n0 + wn * 64 + j * 16 + l16;
#pragma unroll
      for (int r = 0; r < 4; r++)
        out[(size_t)(row + r) * NC + col] = (bf16_t)(acc[i][j][r] * sc);
    }
}

// ------------- G GEMM (SWAP): G[i][e] = hnT[i][:]·Mt[e][:] + u[e]  (u folded in) -------------
__global__ __launch_bounds__(256) void gemm_g_k(const bf16_t* __restrict__ hnT,
                                                const bf16_t* __restrict__ Mt,
                                                const float* __restrict__ u,
                                                bf16_t* __restrict__ G) {
  __shared__ bf16_t As[128 * 64];
  __shared__ bf16_t Bs[128 * 64];
  int n0 = blockIdx.x * 128, m0 = blockIdx.y * 128;
  ACC_INIT(acc);
  gemm_core<NC, true>(hnT, Mt, m0, n0, acc, As, Bs);
  const int lane = threadIdx.x & 63, wv = threadIdx.x >> 6;
  const int l16 = lane & 15, quad = lane >> 4, wm = wv & 1, wn = wv >> 1;
#pragma unroll
  for (int i = 0; i < 4; i++) {
    int m = m0 + wm * 64 + i * 16 + l16;
#pragma unroll
    for (int j = 0; j < 4; j++) {
      int eb = n0 + wn * 64 + j * 16 + quad * 4;
      float4 uv = *(const float4*)&u[eb];
      bf16x4 pk;
      pk[0] = (bf16_t)(acc[i][j][0] + uv.x);
      pk[1] = (bf16_t)(acc[i][j][1] + uv.y);
      pk[2] = (bf16_t)(acc[i][j][2] + uv.z);
      pk[3] = (bf16_t)(acc[i][j][3] + uv.w);
      *(bf16x4*)&G[(size_t)m * NC + eb] = pk;
    }
  }
}

// ------------- S GEMM (SWAP): S[i][j] (fp16) = G[i][:]·hnT[j][:] -------------
__global__ __launch_bounds__(256) void gemm_s_k(const bf16_t* __restrict__ G,
                                                const bf16_t* __restrict__ hnT,
                                                f16_t* __restrict__ S) {
  __shared__ bf16_t As[128 * 64];
  __shared__ bf16_t Bs[128 * 64];
  int bi = blockIdx.z;
  int n0 = blockIdx.x * 128, m0 = blockIdx.y * 128;
  const bf16_t* A = G + (size_t)bi * NHW * NC;
  const bf16_t* B = hnT + (size_t)bi * NHW * NC;
  ACC_INIT(acc);
  gemm_core<NC, true>(A, B, m0, n0, acc, As, Bs);

  const int lane = threadIdx.x & 63, wv = threadIdx.x >> 6;
  const int l16 = lane & 15, quad = lane >> 4, wm = wv & 1, wn = wv >> 1;
  f16_t* out = S + (size_t)bi * NHW * NHW;
#pragma unroll
  for (int i = 0; i < 4; i++) {
    int m = m0 + wm * 64 + i * 16 + l16;
#pragma unroll
    for (int j = 0; j < 4; j++) {
      int nb = n0 + wn * 64 + j * 16 + quad * 4;
      f16x4 pk;
#pragma unroll
      for (int r = 0; r < 4; r++) pk[r] = (f16_t)(acc[i][j][r]);
      *(f16x4*)&out[(size_t)m * NHW + nb] = pk;
    }
  }
}

// ------------- softmax: P (bf16) overwrites S (fp16) in place -------------
__global__ __launch_bounds__(256) void softmax_k(const f16_t* __restrict__ S,
                                                 bf16_t* __restrict__ P) {
  int row = blockIdx.x * 4 + (threadIdx.x >> 6);
  int lane = threadIdx.x & 63;
  const f16_t* sp = S + (size_t)row * NHW + lane * 16;
  f16x8 a = *(const f16x8*)sp;
  f16x8 bq = *(const f16x8*)(sp + 8);
  float v[16];
#pragma unroll
  for (int k = 0; k < 8; k++) { v[k] = (float)a[k]; v[8 + k] = (float)bq[k]; }
  float mx = v[0];
#pragma unroll
  for (int k = 1; k < 16; k++) mx = fmaxf(mx, v[k]);
#pragma unroll
  for (int off = 1; off < 64; off <<= 1) mx = fmaxf(mx, __shfl_xor(mx, off, 64));
  float e[16], s = 0.f;
#pragma unroll
  for (int k = 0; k < 16; k++) { e[k] = exp2f((v[k] - mx) * LOG2E); s += e[k]; }
#pragma unroll
  for (int off = 1; off < 64; off <<= 1) s += __shfl_xor(s, off, 64);
  float inv = 1.f / s;
  bf16x8 o0, o1;
#pragma unroll
  for (int k = 0; k < 8; k++) { o0[k] = (bf16_t)(e[k] * inv); o1[k] = (bf16_t)(e[8 + k] * inv); }
  bf16_t* pp = P + (size_t)row * NHW + lane * 16;
  *(bf16x8*)pp = o0;
  *(bf16x8*)(pp + 8) = o1;
}

// ------------- T GEMM (SWAP): T[n][c] = P[n][:]·hnN[c][:], K=1024 -------------
__global__ __launch_bounds__(256) void gemm_t_k(const bf16_t* __restrict__ P,
                                                const bf16_t* __restrict__ hnN,
                                                bf16_t* __restrict__ T) {
  __shared__ bf16_t As[128 * 64];
  __shared__ bf16_t Bs[128 * 64];
  int bi = blockIdx.z;
  int n0 = blockIdx.x * 128, m0 = blockIdx.y * 128;
  const bf16_t* A = P + (size_t)bi * NHW * NHW;
  const bf16_t* B = hnN + (size_t)bi * NC * NHW;
  ACC_INIT(acc);
  gemm_core<NHW, true>(A, B, m0, n0, acc, As, Bs);

  const int lane = threadIdx.x & 63, wv = threadIdx.x >> 6;
  const int l16 = lane & 15, quad = lane >> 4, wm = wv & 1, wn = wv >> 1;
  bf16_t* out = T + (size_t)bi * NHW * NC;
#pragma unroll
  for (int i = 0; i < 4; i++) {
    int m = m0 + wm * 64 + i * 16 + l16;
#pragma unroll
    for (int j = 0; j < 4; j++) {
      int cb = n0 + wn * 64 + j * 16 + quad * 4;
      bf16x4 pk;
#pragma unroll
      for (int r = 0; r < 4; r++) pk[r] = (bf16_t)(acc[i][j][r]);
      *(bf16x4*)&out[(size_t)m * NC + cb] = pk;
    }
  }
}

// ------------- final GEMM: out[d][n] (fp32) = T·W23t + bb + x -------------
__global__ __launch_bounds__(256) void gemm_out_k(const bf16_t* __restrict__ T,
                                                  const bf16_t* __restrict__ W23t,
                                                  const float* __restrict__ bb,
                                                  const float* __restrict__ x,
                                                  float* __restrict__ outp) {
  __shared__ bf16_t As[128 * 64];
  __shared__ bf16_t Bs[128 * 64];
  int bi = blockIdx.z;
  int n0 = blockIdx.x * 128, m0 = blockIdx.y * 128;
  const bf16_t* A = T + (size_t)bi * NHW * NC;
  ACC_INIT(acc);
  gemm_core<NC, false>(A, W23t, m0, n0, acc, As, Bs);

  const int lane = threadIdx.x & 63, wv = threadIdx.x >> 6;
  const int l16 = lane & 15, quad = lane >> 4, wm = wv & 1, wn = wv >> 1;
  const float* xb = x + (size_t)bi * NC * NHW;
  float* ob = outp + (size_t)bi * NC * NHW;
#pragma unroll
  for (int i = 0; i < 4; i++)
#pragma unroll
    for (int j = 0; j < 4; j++) {
      int row = m0 + wm * 64 + i * 16 + quad * 4;  // spatial n
      int col = n0 + wn * 64 + j * 16 + l16;       // channel d
      float bv = bb[col];
      size_t base = (size_t)col * NHW + row;
      float4 xv = *(const float4*)&xb[base];
      float4 pk;
      pk.x = acc[i][j][0] + bv + xv.x;
      pk.y = acc[i][j][1] + bv + xv.y;
      pk.z = acc[i][j][2] + bv + xv.z;
      pk.w = acc[i][j][3] + bv + xv.w;
      *(float4*)&ob[base] = pk;
    }
}

extern "C" void kernel_launch(void* const* d_in, const int* in_sizes, int n_in,
                              void* d_out, int out_size, void* d_ws, size_t ws_size,
                              hipStream_t stream) {
  (void)in_sizes; (void)n_in; (void)out_size; (void)ws_size;
  const float* x     = (const float*)d_in[0];
  const float* gamma = (const float*)d_in[1];
  const float* beta  = (const float*)d_in[2];
  const float* W0    = (const float*)d_in[3];
  const float* b0    = (const float*)d_in[4];
  const float* W1    = (const float*)d_in[5];
  const float* b1    = (const float*)d_in[6];  (void)b1;  // cancels in softmax
  const float* W2    = (const float*)d_in[7];
  const float* b2    = (const float*)d_in[8];
  const float* W3    = (const float*)d_in[9];
  const float* b3    = (const float*)d_in[10];
  float* outp = (float*)d_out;

  char* ws = (char*)d_ws;
  const size_t PLANE = (size_t)NB * NHW * NC * sizeof(bf16_t);  // 16 MB
  float* stats = (float*)ws;
  size_t off = 4096;
  bf16_t* hnT = (bf16_t*)(ws + off); off += PLANE;
  bf16_t* hnN = (bf16_t*)(ws + off); off += PLANE;
  bf16_t* G   = (bf16_t*)(ws + off); off += PLANE;   // reused as T after gemm_s
  bf16_t* Wt  = (bf16_t*)(ws + off); off += 4 * (size_t)NC * NC * sizeof(bf16_t);
  bf16_t* Mt   = (bf16_t*)(ws + off); off += (size_t)NC * NC * sizeof(bf16_t);
  bf16_t* W23t = (bf16_t*)(ws + off); off += (size_t)NC * NC * sizeof(bf16_t);
  float*  u   = (float*)(ws + off);  off += 2048;
  float*  bb  = (float*)(ws + off);  off += 2048;
  f16_t*  S   = (f16_t*)(ws + off);  off += (size_t)NB * NHW * NHW * sizeof(f16_t);  // 32 MB
  bf16_t* P   = (bf16_t*)S;   // softmax writes bf16 in place
  bf16_t* T   = G;            // G dead after gemm_s

  prep1_k<<<dim3(16, 16, 7), 256, 0, stream>>>(x, W0, W1, W2, W3, b0, b2, b3, Wt, u, bb, stats);
  prep2_k<<<dim3(32, 16, NB + 1), 256, 0, stream>>>(x, gamma, beta, stats, Wt, hnT, hnN, Mt, W23t);
  gemm_g_k<<<dim3(4, 128), 256, 0, stream>>>(hnT, Mt, u, G);
  gemm_s_k<<<dim3(8, 8, NB), 256, 0, stream>>>(G, hnT, S);
  softmax_k<<<dim3(NB * NHW / 4), 256, 0, stream>>>(S, P);
  gemm_t_k<<<dim3(4, 8, NB), 256, 0, stream>>>(P, hnN, T);
  gemm_out_k<<<dim3(4, 8, NB), 256, 0, stream>>>(T, W23t, bb, x, outp);
}